// Round 4
// baseline (433.913 us; speedup 1.0000x reference)
//
#include <hip/hip_runtime.h>
#include <hip/hip_bf16.h>

typedef unsigned short u16;
typedef unsigned int u32;
typedef __attribute__((ext_vector_type(8))) short short8;   // 8 x bf16 frag
typedef __attribute__((ext_vector_type(4))) short short4v;  // 4 x bf16 pack
typedef __attribute__((ext_vector_type(16))) float f32x16;  // 32x32 acc
typedef __attribute__((ext_vector_type(4))) float f32x4;    // 16x16 acc

#define MFMA32 __builtin_amdgcn_mfma_f32_32x32x16_bf16
#define MFMA16 __builtin_amdgcn_mfma_f32_16x16x32_bf16

#define NSEQ 4096
#define CD 256
// (1/sqrt(256)) * log2(e) = 0.0625 * 1.4426950408889634  -- EXACT.
#define CF 0.09016844005556021f

__device__ __forceinline__ u16 f2bf(float f) {
  u32 u = __float_as_uint(f);
  u += 0x7fffu + ((u >> 16) & 1u);  // RNE
  return (u16)(u >> 16);
}
__device__ __forceinline__ float bf2f(short s) {
  return __uint_as_float(((u32)(u16)s) << 16);
}
// HW packed f32x2 -> bf16x2 (gfx950 v_cvt_pk_bf16_f32), RNE
__device__ __forceinline__ u32 pk2bf(float a, float b) {
  union {
    __hip_bfloat162 h;
    u32 u;
  } cv;
  cv.h = __float22bfloat162_rn(make_float2(a, b));
  return cv.u;
}
// async global -> LDS DMA, 16B per lane; LDS dest = wave-uniform base + lane*16
__device__ __forceinline__ void async16(const void* g, void* l) {
  __builtin_amdgcn_global_load_lds(
      (const __attribute__((address_space(1))) u32*)g,
      (__attribute__((address_space(3))) u32*)l, 16, 0, 0);
}

// ---------------------------------------------------------------------------
// transpose-cast x: (b, 256, 4096) f32 -> x_t (b, 4096, 256) bf16
// + folded weight cast (1024 blocks x 256 weight elems = exactly 768*256+256*256)
// ---------------------------------------------------------------------------
__global__ __launch_bounds__(256) void xpose_cast(const float* __restrict__ x,
                                                  u16* __restrict__ x_t,
                                                  const float* __restrict__ qkv_w,
                                                  const float* __restrict__ out_w,
                                                  u16* __restrict__ wq,
                                                  u16* __restrict__ wo) {
  __shared__ float tile[64][65];
  const int t = threadIdx.x;
  // ---- weight cast slice ----
  {
    int lin = blockIdx.x + 64 * (blockIdx.y + 4 * blockIdx.z);
    int widx = lin * 256 + t;
    if (widx < 768 * CD)
      wq[widx] = f2bf(qkv_w[widx]);
    else
      wo[widx - 768 * CD] = f2bf(out_w[widx - 768 * CD]);
  }
  // ---- transpose-cast ----
  const int b = blockIdx.z;
  const int n0 = blockIdx.x * 64, c0 = blockIdx.y * 64;
  const float* xb = x + (size_t)b * CD * NSEQ;
  const int cr = t >> 4, nc4 = (t & 15) * 4;
#pragma unroll
  for (int i = 0; i < 4; ++i) {
    int c = cr + 16 * i;
    float4 v = *(const float4*)(xb + (size_t)(c0 + c) * NSEQ + n0 + nc4);
    tile[c][nc4 + 0] = v.x;
    tile[c][nc4 + 1] = v.y;
    tile[c][nc4 + 2] = v.z;
    tile[c][nc4 + 3] = v.w;
  }
  __syncthreads();
  const int n = t & 63, cc = (t >> 6) * 16;
  u16* dst = x_t + (size_t)b * NSEQ * CD + (size_t)(n0 + n) * CD + c0 + cc;
#pragma unroll
  for (int j = 0; j < 4; ++j) {
    short4v pv;
#pragma unroll
    for (int r = 0; r < 4; ++r) pv[r] = (short)f2bf(tile[cc + 4 * j + r][n]);
    *(short4v*)(dst + 4 * j) = pv;
  }
}

// ---------------------------------------------------------------------------
// QKV projection, 128x128 tile, 512 threads (8 waves), 32x32x16 MFMA.
// (unchanged)
// ---------------------------------------------------------------------------
__global__ __launch_bounds__(512, 1) void qkv_gemm3(
    const u16* __restrict__ wq, const float* __restrict__ qkv_b,
    const u16* __restrict__ x_t, u16* __restrict__ q_t, u16* __restrict__ k_t,
    u16* __restrict__ v_) {
  __shared__ u16 __align__(16) Wls[128 * 256];
  __shared__ u16 __align__(16) Bls[128 * 256];
  const int t = threadIdx.x, w = t >> 6, lane = t & 63;
  const int l31 = lane & 31, l5 = lane >> 5;
  const int os = w & 3, nh = w >> 2;
  const int n0 = blockIdx.x * 128, o0 = blockIdx.y * 128, b = blockIdx.z;
  const u16* Xb = x_t + (size_t)b * NSEQ * CD;
#pragma unroll
  for (int j = 0; j < 8; ++j) {
    int r = w * 16 + j * 2 + l5;
    async16(wq + (size_t)(o0 + r) * CD + ((l31 ^ (r & 7)) * 8),
            Wls + (w * 16 + j * 2) * 256);
    async16(Xb + (size_t)(n0 + r) * CD + ((l31 ^ (r & 7)) * 8),
            Bls + (w * 16 + j * 2) * 256);
  }
  __builtin_amdgcn_s_waitcnt(0);
  __syncthreads();
  f32x16 acc0, acc1;
#pragma unroll
  for (int i = 0; i < 16; ++i) {
    acc0[i] = 0.f;
    acc1[i] = 0.f;
  }
  const int ra = os * 32 + l31;
  const int rb0 = nh * 64 + l31, rb1 = rb0 + 32;
#pragma unroll
  for (int kc = 0; kc < 16; ++kc) {
    short8 a = *(const short8*)(Wls + ra * 256 + (((kc * 2 + l5) ^ (ra & 7)) * 8));
    short8 b0 = *(const short8*)(Bls + rb0 * 256 + (((kc * 2 + l5) ^ (rb0 & 7)) * 8));
    short8 b1 = *(const short8*)(Bls + rb1 * 256 + (((kc * 2 + l5) ^ (rb1 & 7)) * 8));
    acc0 = MFMA32(a, b0, acc0, 0, 0, 0);
    acc1 = MFMA32(a, b1, acc1, 0, 0, 0);
  }
  const int otype = blockIdx.y >> 1;  // 0=Q 1=K 2=V
  const int obase = o0 + os * 32;
#pragma unroll
  for (int na = 0; na < 2; ++na) {
    f32x16& acc = na ? acc1 : acc0;
    const int n_g = n0 + nh * 64 + na * 32 + l31;
    if (otype < 2) {
      u16* dst = (otype == 0 ? q_t : k_t) + (size_t)b * NSEQ * CD +
                 (size_t)n_g * CD + (obase - otype * 256);
#pragma unroll
      for (int g = 0; g < 4; ++g) {
        float4 bv = *(const float4*)(qkv_b + obase + g * 8 + l5 * 4);
        const float* bp = (const float*)&bv;
        short4v pk;
#pragma unroll
        for (int r = 0; r < 4; ++r) pk[r] = (short)f2bf(acc[g * 4 + r] + bp[r]);
        *(short4v*)(dst + g * 8 + l5 * 4) = pk;
      }
    } else {
      u16* dst = v_ + (size_t)b * CD * NSEQ;
#pragma unroll
      for (int g = 0; g < 4; ++g) {
        float4 bv = *(const float4*)(qkv_b + obase + g * 8 + l5 * 4);
        const float* bp = (const float*)&bv;
#pragma unroll
        for (int r = 0; r < 4; ++r) {
          int c = obase - 512 + g * 8 + l5 * 4 + r;
          dst[(size_t)c * NSEQ + n_g] = f2bf(acc[g * 4 + r] + bp[r]);
        }
      }
    }
  }
}

// ---------------------------------------------------------------------------
// Flash attention v10: V off the LDS pipe. Post-mortem of v9: occupancy
// doubled as predicted but per-CU LDS read demand doubled with it (every
// wave reads the full shared K+V tiles: 1KB/key/wave) -> LDS-pipe-bound at
// ~70% of wall, dur regressed 111->137us. The LDS-traffic invariant means
// occupancy-via-smaller-m cannot win while both K and V ride the LDS pipe.
// Fix: V-frags read DIRECTLY from global (v_ is (b,256c,4096n); lane reads
// V[ct*16+l15][key g*8..+7] = 16B contiguous) -> V traffic moves to the
// parallel VMEM/L1 pipe (V tile shared by all waves on the CU -> L2 first
// touch, L1 after). Bit-identical numerics to v9. K stays LDS-DMA'd
// (double-buffered, swizzled). 256-thread blocks (4 waves x 16m = 64m,
// grid 1024) for fine occupancy quantization; launch_bounds(256,3) targets
// 12 waves/CU. V consumed via 8-deep register pipeline: 8 preloaded under
// softmax/butterfly, rolling +8 ahead under the PV MFMAs.
// ---------------------------------------------------------------------------
__global__ __launch_bounds__(256, 3) void flash10(const u16* __restrict__ q_t,
                                                  const u16* __restrict__ k_t,
                                                  const u16* __restrict__ v_,
                                                  u16* __restrict__ opart,
                                                  float2* __restrict__ ml) {
  __shared__ u16 __align__(16) Kls[2][32 * 256];  // [buf][n][c] swizzled

  const int t = threadIdx.x, w = t >> 6, lane = t & 63;
  const int l31 = lane & 31, l5 = lane >> 5;
  const int l15 = lane & 15, g = lane >> 4;

  // XCD swizzle: xcd owns (b, quarter-pair); 1024 blocks, 1024%8==0 ✓.
  const int linear = blockIdx.x;
  const int xcd = linear & 7, slot = linear >> 3;  // slot in [0,128)
  const int b = xcd >> 1;
  const int q = (xcd & 1) * 2 + (slot >> 6);  // key-quarter 0..3
  const int mblk = slot & 63;
  const int m0 = mblk * 64;
  const int nbase = q * 1024;

  const u16* Qb = q_t + (size_t)b * NSEQ * CD;
  const u16* Kb = k_t + (size_t)b * NSEQ * CD;
  const u16* Vb = v_ + (size_t)b * CD * NSEQ;

  const int mrow = m0 + w * 16 + l15;  // global query index (col = l15)

  // Q fragments in registers (B-operand for S), K=256: 8 x short8 = 32 VGPRs
  short8 qf[8];
#pragma unroll
  for (int kk = 0; kk < 8; ++kk)
    qf[kk] = *(const short8*)(Qb + (size_t)mrow * CD + kk * 32 + g * 8);

  // K staging: wave w stages rows w*8 + j*2 + l5 (2 rows per 1KB DMA, 4 DMAs)
  const u16* ksrc[4];
#pragma unroll
  for (int j = 0; j < 4; ++j) {
    int kr = w * 8 + j * 2 + l5;
    ksrc[j] = Kb + (size_t)kr * CD + ((l31 ^ (kr & 7)) * 8);
  }

  // stage tile 0 into buf 0
#pragma unroll
  for (int j = 0; j < 4; ++j)
    async16(ksrc[j] + (size_t)nbase * CD, &Kls[0][(w * 8 + j * 2) * 256]);

  float mst = -3.0e38f, lst = 0.f;
  f32x4 oa[16];  // O[c = ct*16 + g*4 + r][m = l15]: 64 regs
#pragma unroll
  for (int i = 0; i < 16; ++i)
#pragma unroll
    for (int r = 0; r < 4; ++r) oa[i][r] = 0.f;

  const int kx = l15 & 7;  // K chunk xor (same for both subtiles)
  // V global base for this lane: row c = l15 (+ct*16), keys g*8..+7
  const u16* vlane = Vb + (size_t)l15 * NSEQ + nbase + g * 8;

  for (int tt = 0; tt < 32; ++tt) {
    const int cur = tt & 1;
    // drain: tile tt's K DMA complete; prior reads of buf[cur] done
    __builtin_amdgcn_s_waitcnt(0);
    __syncthreads();
    if (tt + 1 < 32) {
      const int n0 = nbase + (tt + 1) * 32;
      const int nxt = cur ^ 1;
#pragma unroll
      for (int j = 0; j < 4; ++j)
        async16(ksrc[j] + (size_t)n0 * CD, &Kls[nxt][(w * 8 + j * 2) * 256]);
    }
    // ---- S = K . Q^T : two independent 16-key subtiles, K=256 ----
    f32x4 sa0, sa1;
#pragma unroll
    for (int r = 0; r < 4; ++r) {
      sa0[r] = 0.f;
      sa1[r] = 0.f;
    }
    __builtin_amdgcn_s_setprio(1);
#pragma unroll
    for (int kk = 0; kk < 8; ++kk) {
      const int ch = kk * 4 + g;  // logical chunk; xor affects low 3 bits
      short8 a0 = *(const short8*)(&Kls[cur][l15 * 256 + ((ch ^ kx) * 8)]);
      short8 a1 =
          *(const short8*)(&Kls[cur][(16 + l15) * 256 + ((ch ^ kx) * 8)]);
      sa0 = MFMA16(a0, qf[kk], sa0, 0, 0, 0);
      sa1 = MFMA16(a1, qf[kk], sa1, 0, 0, 0);
    }
    __builtin_amdgcn_s_setprio(0);
    // ---- softmax: lane holds 8 scores for m=l15 (keys 16t+4g+r);
    //      4 lanes per m merge via shfl_xor 16,32 ----
    float rm = fmaxf(fmaxf(fmaxf(sa0[0], sa0[1]), fmaxf(sa0[2], sa0[3])),
                     fmaxf(fmaxf(sa1[0], sa1[1]), fmaxf(sa1[2], sa1[3])));
    rm = fmaxf(rm, __shfl_xor(rm, 16));
    rm = fmaxf(rm, __shfl_xor(rm, 32));
    float mnew = fmaxf(mst, rm * CF);
    float al = exp2f(mst - mnew);
    mst = mnew;
    float p00 = exp2f(sa0[0] * CF - mnew), p01 = exp2f(sa0[1] * CF - mnew);
    float p02 = exp2f(sa0[2] * CF - mnew), p03 = exp2f(sa0[3] * CF - mnew);
    float p10 = exp2f(sa1[0] * CF - mnew), p11 = exp2f(sa1[1] * CF - mnew);
    float p12 = exp2f(sa1[2] * CF - mnew), p13 = exp2f(sa1[3] * CF - mnew);
    float ls = ((p00 + p01) + (p02 + p03)) + ((p10 + p11) + (p12 + p13));
    ls += __shfl_xor(ls, 16);
    ls += __shfl_xor(ls, 32);
    lst = lst * al + ls;
    // ---- V pipeline: issue first 8 global V loads (hide under
    //      butterfly + rescale; L1/L2-resident tile) ----
    const u16* vt = vlane + tt * 32;
    short8 vr[8];
#pragma unroll
    for (int i = 0; i < 8; ++i)
      vr[i] = *(const short8*)(vt + (size_t)i * 16 * NSEQ);
    // ---- rescale O only when the running max moved ----
    if (__ballot(al != 1.0f)) {
#pragma unroll
      for (int i = 0; i < 16; ++i)
#pragma unroll
        for (int r = 0; r < 4; ++r) oa[i][r] *= al;
    }
    // ---- P -> B-frag: 4x4 dword butterfly across g-groups ----
    u32 A0 = pk2bf(p00, p01), A1 = pk2bf(p02, p03);
    u32 B0 = pk2bf(p10, p11), B1 = pk2bf(p12, p13);
    const int g0 = g & 1, h = g >> 1;
    u32 ea0 = (u32)__shfl_xor((int)A0, 16), ea1 = (u32)__shfl_xor((int)A1, 16);
    u32 eb0 = (u32)__shfl_xor((int)B0, 16), eb1 = (u32)__shfl_xor((int)B1, 16);
    u32 CA0 = g0 ? ea0 : A0, CA1 = g0 ? ea1 : A1;
    u32 CA2 = g0 ? A0 : ea0, CA3 = g0 ? A1 : ea1;
    u32 CB0 = g0 ? eb0 : B0, CB1 = g0 ? eb1 : B1;
    u32 CB2 = g0 ? B0 : eb0, CB3 = g0 ? B1 : eb1;
    u32 s0 = h ? CA0 : CB0, s1 = h ? CA1 : CB1;
    u32 s2 = h ? CA2 : CB2, s3 = h ? CA3 : CB3;
    u32 r0 = (u32)__shfl_xor((int)s0, 32), r1 = (u32)__shfl_xor((int)s1, 32);
    u32 r2 = (u32)__shfl_xor((int)s2, 32), r3 = (u32)__shfl_xor((int)s3, 32);
    u32 k0 = h ? CB0 : CA0, k1 = h ? CB1 : CA1;
    u32 k2 = h ? CB2 : CA2, k3 = h ? CB3 : CA3;
    const bool own = (g0 == h);
    union {
      u32 u[4];
      short8 s8;
    } pfv;
    pfv.u[0] = own ? k0 : r0;
    pfv.u[1] = own ? k1 : r1;
    pfv.u[2] = own ? k2 : r2;
    pfv.u[3] = own ? k3 : r3;
    short8 pf = pfv.s8;
    // ---- O += V . P : 16 c-subtiles, V from global regs (8-deep roll) ----
    __builtin_amdgcn_s_setprio(1);
#pragma unroll
    for (int ct = 0; ct < 16; ++ct) {
      short8 cv = vr[ct & 7];
      if (ct < 8) vr[ct & 7] = *(const short8*)(vt + (size_t)(ct + 8) * 16 * NSEQ);
      oa[ct] = MFMA16(cv, pf, oa[ct], 0, 0, 0);
    }
    __builtin_amdgcn_s_setprio(0);
  }

  // ---- finalize: per-stream normalized O -> bf16; (m,l) for merge ----
  float inv = 1.0f / lst;
  u16* dst = opart + ((size_t)(q * 4 + b) * NSEQ + mrow) * CD;
#pragma unroll
  for (int ct = 0; ct < 16; ++ct) {
    short4v pk;
#pragma unroll
    for (int r = 0; r < 4; ++r) pk[r] = (short)f2bf(oa[ct][r] * inv);
    *(short4v*)(dst + ct * 16 + g * 4) = pk;
  }
  if (lane < 16)
    ml[(size_t)(q * 4 + b) * NSEQ + mrow] = make_float2(mst, lst);
}

// ---------------------------------------------------------------------------
// out projection + 4-stream split-key merge folded into B-tile staging.
// (unchanged)
// ---------------------------------------------------------------------------
__global__ __launch_bounds__(512, 1) void out_gemm6(
    const u16* __restrict__ wo, const float* __restrict__ out_b,
    const u16* __restrict__ opart, const float2* __restrict__ ml,
    float* __restrict__ out) {
  __shared__ u16 __align__(16) Wls[128 * 256];
  __shared__ u16 __align__(16) Bls[128 * 256];
  const int t = threadIdx.x, w = t >> 6, lane = t & 63;
  const int l31 = lane & 31, l5 = lane >> 5;
  const int os = w & 3, nh = w >> 2;
  const int n0 = blockIdx.x * 128, o0 = blockIdx.y * 128, b = blockIdx.z;
#pragma unroll
  for (int j = 0; j < 8; ++j) {
    int r = w * 16 + j * 2 + l5;
    async16(wo + (size_t)(o0 + r) * CD + ((l31 ^ (r & 7)) * 8),
            Wls + (w * 16 + j * 2) * 256);
  }
#pragma unroll
  for (int i = 0; i < 8; ++i) {
    int idx = i * 512 + t;
    int r = idx >> 5, p = idx & 31;
    int n = n0 + r;
    float2 st[4];
#pragma unroll
    for (int qq = 0; qq < 4; ++qq) st[qq] = ml[(size_t)(qq * 4 + b) * NSEQ + n];
    float M = fmaxf(fmaxf(st[0].x, st[1].x), fmaxf(st[2].x, st[3].x));
    float wt[4], tot = 0.f;
#pragma unroll
    for (int qq = 0; qq < 4; ++qq) {
      wt[qq] = st[qq].y * exp2f(st[qq].x - M);
      tot += wt[qq];
    }
    float inv = 1.0f / tot;
    float acc[8] = {};
#pragma unroll
    for (int qq = 0; qq < 4; ++qq) {
      float wq_ = wt[qq] * inv;
      short8 xq =
          *(const short8*)(opart + ((size_t)(qq * 4 + b) * NSEQ + n) * CD + p * 8);
#pragma unroll
      for (int e = 0; e < 8; ++e) acc[e] += wq_ * bf2f(xq[e]);
    }
    short8 om;
#pragma unroll
    for (int e = 0; e < 8; ++e) om[e] = (short)f2bf(acc[e]);
    *(short8*)(Bls + r * 256 + ((p ^ (r & 7)) * 8)) = om;
  }
  __builtin_amdgcn_s_waitcnt(0);
  __syncthreads();
  f32x16 acc0, acc1;
#pragma unroll
  for (int i = 0; i < 16; ++i) {
    acc0[i] = 0.f;
    acc1[i] = 0.f;
  }
  const int ra = os * 32 + l31;
  const int rb0 = nh * 64 + l31, rb1 = rb0 + 32;
#pragma unroll
  for (int kc = 0; kc < 16; ++kc) {
    short8 a = *(const short8*)(Wls + ra * 256 + (((kc * 2 + l5) ^ (ra & 7)) * 8));
    short8 b0 = *(const short8*)(Bls + rb0 * 256 + (((kc * 2 + l5) ^ (rb0 & 7)) * 8));
    short8 b1 = *(const short8*)(Bls + rb1 * 256 + (((kc * 2 + l5) ^ (rb1 & 7)) * 8));
    acc0 = MFMA32(a, b0, acc0, 0, 0, 0);
    acc1 = MFMA32(a, b1, acc1, 0, 0, 0);
  }
  const int obase = o0 + os * 32;
#pragma unroll
  for (int na = 0; na < 2; ++na) {
    f32x16& acc = na ? acc1 : acc0;
    const int n_g = n0 + nh * 64 + na * 32 + l31;
#pragma unroll
    for (int g = 0; g < 4; ++g) {
      float4 bv = *(const float4*)(out_b + obase + g * 8 + l5 * 4);
      const float* bp = (const float*)&bv;
#pragma unroll
      for (int r = 0; r < 4; ++r) {
        int o = obase + g * 8 + l5 * 4 + r;
        out[((size_t)b * CD + o) * NSEQ + n_g] = acc[g * 4 + r] + bp[r];
      }
    }
  }
}

// ---------------------------------------------------------------------------
extern "C" void kernel_launch(void* const* d_in, const int* in_sizes, int n_in,
                              void* d_out, int out_size, void* d_ws,
                              size_t ws_size, hipStream_t stream) {
  const float* x = (const float*)d_in[0];
  const float* qkv_w = (const float*)d_in[1];
  const float* qkv_b = (const float*)d_in[2];
  const float* out_w = (const float*)d_in[3];
  const float* out_b = (const float*)d_in[4];
  float* out = (float*)d_out;

  const size_t SZ = (size_t)4 * NSEQ * CD;  // elems per (b,4096,256) bf16
  u16* x_t = (u16*)d_ws;
  u16* q_t = x_t + SZ;
  u16* k_t = q_t + SZ;
  u16* v_ = k_t + SZ;
  u16* opart = v_ + SZ;              // 4 key-stream quarters, 4*SZ
  u16* wq = opart + 4 * SZ;          // 768*256
  u16* wo = wq + 768 * CD;           // 256*256
  float2* ml = (float2*)(wo + CD * CD);  // 4*4*4096 float2

  xpose_cast<<<dim3(64, 4, 4), dim3(256), 0, stream>>>(x, x_t, qkv_w, out_w,
                                                       wq, wo);
  qkv_gemm3<<<dim3(32, 6, 4), dim3(512), 0, stream>>>(wq, qkv_b, x_t, q_t, k_t,
                                                      v_);
  flash10<<<dim3(1024), dim3(256), 0, stream>>>(q_t, k_t, v_, opart, ml);
  out_gemm6<<<dim3(32, 2, 4), dim3(512), 0, stream>>>(wo, out_b, opart, ml,
                                                      out);
}

// Round 5
// 210.967 us; speedup vs baseline: 2.0568x; 2.0568x over previous
//
#include <hip/hip_runtime.h>
#include <hip/hip_bf16.h>

typedef unsigned short u16;
typedef unsigned int u32;
typedef __attribute__((ext_vector_type(8))) short short8;   // 8 x bf16 frag
typedef __attribute__((ext_vector_type(4))) short short4v;  // 4 x bf16 pack
typedef __attribute__((ext_vector_type(16))) float f32x16;  // 32x32 acc

#define MFMA32 __builtin_amdgcn_mfma_f32_32x32x16_bf16

#define NSEQ 4096
#define CD 256
// (1/sqrt(256)) * log2(e) = 0.0625 * 1.4426950408889634  -- EXACT.
#define CF 0.09016844005556021f

__device__ __forceinline__ u16 f2bf(float f) {
  u32 u = __float_as_uint(f);
  u += 0x7fffu + ((u >> 16) & 1u);  // RNE
  return (u16)(u >> 16);
}
__device__ __forceinline__ float bf2f(short s) {
  return __uint_as_float(((u32)(u16)s) << 16);
}
// HW packed f32x2 -> bf16x2 (gfx950 v_cvt_pk_bf16_f32), RNE
__device__ __forceinline__ u32 pk2bf(float a, float b) {
  union {
    __hip_bfloat162 h;
    u32 u;
  } cv;
  cv.h = __float22bfloat162_rn(make_float2(a, b));
  return cv.u;
}
// async global -> LDS DMA, 16B per lane; LDS dest = wave-uniform base + lane*16
__device__ __forceinline__ void async16(const void* g, void* l) {
  __builtin_amdgcn_global_load_lds(
      (const __attribute__((address_space(1))) u32*)g,
      (__attribute__((address_space(3))) u32*)l, 16, 0, 0);
}

// ---------------------------------------------------------------------------
// transpose-cast x: (b, 256, 4096) f32 -> x_t (b, 4096, 256) bf16
// + folded weight cast (1024 blocks x 256 weight elems = exactly 768*256+256*256)
// ---------------------------------------------------------------------------
__global__ __launch_bounds__(256) void xpose_cast(const float* __restrict__ x,
                                                  u16* __restrict__ x_t,
                                                  const float* __restrict__ qkv_w,
                                                  const float* __restrict__ out_w,
                                                  u16* __restrict__ wq,
                                                  u16* __restrict__ wo) {
  __shared__ float tile[64][65];
  const int t = threadIdx.x;
  // ---- weight cast slice ----
  {
    int lin = blockIdx.x + 64 * (blockIdx.y + 4 * blockIdx.z);
    int widx = lin * 256 + t;
    if (widx < 768 * CD)
      wq[widx] = f2bf(qkv_w[widx]);
    else
      wo[widx - 768 * CD] = f2bf(out_w[widx - 768 * CD]);
  }
  // ---- transpose-cast ----
  const int b = blockIdx.z;
  const int n0 = blockIdx.x * 64, c0 = blockIdx.y * 64;
  const float* xb = x + (size_t)b * CD * NSEQ;
  const int cr = t >> 4, nc4 = (t & 15) * 4;
#pragma unroll
  for (int i = 0; i < 4; ++i) {
    int c = cr + 16 * i;
    float4 v = *(const float4*)(xb + (size_t)(c0 + c) * NSEQ + n0 + nc4);
    tile[c][nc4 + 0] = v.x;
    tile[c][nc4 + 1] = v.y;
    tile[c][nc4 + 2] = v.z;
    tile[c][nc4 + 3] = v.w;
  }
  __syncthreads();
  const int n = t & 63, cc = (t >> 6) * 16;
  u16* dst = x_t + (size_t)b * NSEQ * CD + (size_t)(n0 + n) * CD + c0 + cc;
#pragma unroll
  for (int j = 0; j < 4; ++j) {
    short4v pv;
#pragma unroll
    for (int r = 0; r < 4; ++r) pv[r] = (short)f2bf(tile[cc + 4 * j + r][n]);
    *(short4v*)(dst + 4 * j) = pv;
  }
}

// ---------------------------------------------------------------------------
// QKV projection, 128x128 tile, 512 threads (8 waves), 32x32x16 MFMA.
// ---------------------------------------------------------------------------
__global__ __launch_bounds__(512, 1) void qkv_gemm3(
    const u16* __restrict__ wq, const float* __restrict__ qkv_b,
    const u16* __restrict__ x_t, u16* __restrict__ q_t, u16* __restrict__ k_t,
    u16* __restrict__ v_) {
  __shared__ u16 __align__(16) Wls[128 * 256];
  __shared__ u16 __align__(16) Bls[128 * 256];
  const int t = threadIdx.x, w = t >> 6, lane = t & 63;
  const int l31 = lane & 31, l5 = lane >> 5;
  const int os = w & 3, nh = w >> 2;
  const int n0 = blockIdx.x * 128, o0 = blockIdx.y * 128, b = blockIdx.z;
  const u16* Xb = x_t + (size_t)b * NSEQ * CD;
#pragma unroll
  for (int j = 0; j < 8; ++j) {
    int r = w * 16 + j * 2 + l5;
    async16(wq + (size_t)(o0 + r) * CD + ((l31 ^ (r & 7)) * 8),
            Wls + (w * 16 + j * 2) * 256);
    async16(Xb + (size_t)(n0 + r) * CD + ((l31 ^ (r & 7)) * 8),
            Bls + (w * 16 + j * 2) * 256);
  }
  __builtin_amdgcn_s_waitcnt(0);
  __syncthreads();
  f32x16 acc0, acc1;
#pragma unroll
  for (int i = 0; i < 16; ++i) {
    acc0[i] = 0.f;
    acc1[i] = 0.f;
  }
  const int ra = os * 32 + l31;
  const int rb0 = nh * 64 + l31, rb1 = rb0 + 32;
#pragma unroll
  for (int kc = 0; kc < 16; ++kc) {
    short8 a = *(const short8*)(Wls + ra * 256 + (((kc * 2 + l5) ^ (ra & 7)) * 8));
    short8 b0 = *(const short8*)(Bls + rb0 * 256 + (((kc * 2 + l5) ^ (rb0 & 7)) * 8));
    short8 b1 = *(const short8*)(Bls + rb1 * 256 + (((kc * 2 + l5) ^ (rb1 & 7)) * 8));
    acc0 = MFMA32(a, b0, acc0, 0, 0, 0);
    acc1 = MFMA32(a, b1, acc1, 0, 0, 0);
  }
  const int otype = blockIdx.y >> 1;  // 0=Q 1=K 2=V
  const int obase = o0 + os * 32;
#pragma unroll
  for (int na = 0; na < 2; ++na) {
    f32x16& acc = na ? acc1 : acc0;
    const int n_g = n0 + nh * 64 + na * 32 + l31;
    if (otype < 2) {
      u16* dst = (otype == 0 ? q_t : k_t) + (size_t)b * NSEQ * CD +
                 (size_t)n_g * CD + (obase - otype * 256);
#pragma unroll
      for (int g = 0; g < 4; ++g) {
        float4 bv = *(const float4*)(qkv_b + obase + g * 8 + l5 * 4);
        const float* bp = (const float*)&bv;
        short4v pk;
#pragma unroll
        for (int r = 0; r < 4; ++r) pk[r] = (short)f2bf(acc[g * 4 + r] + bp[r]);
        *(short4v*)(dst + g * 8 + l5 * 4) = pk;
      }
    } else {
      u16* dst = v_ + (size_t)b * CD * NSEQ;
#pragma unroll
      for (int g = 0; g < 4; ++g) {
        float4 bv = *(const float4*)(qkv_b + obase + g * 8 + l5 * 4);
        const float* bp = (const float*)&bv;
#pragma unroll
        for (int r = 0; r < 4; ++r) {
          int c = obase - 512 + g * 8 + l5 * 4 + r;
          dst[(size_t)c * NSEQ + n_g] = f2bf(acc[g * 4 + r] + bp[r]);
        }
      }
    }
  }
}

// ---------------------------------------------------------------------------
// Flash attention v8b: REVERT to the 111.4us champion structure (v8) after
// v9 (occupancy 2x -> LDS traffic 2x, 137us) and v10 (V-from-global, VMEM
// latency, 350us) both regressed. The design space is pinned: LDS traffic
// = (K+V tiles) x 256m / m-per-wave, register file = 256/wave at 32m/wave
// (exactly 2 waves/SIMD). v8 is the optimum of this family.
// Single micro-fix vs v8: per-lane lst partials -- al/mnew are uniform
// across the l5 pair, so the lst recurrence is linear with pair-uniform
// coefficients; keep per-lane partial sums and merge with ONE shfl at
// finalize instead of one shfl_xor(32) in every iteration's serial chain.
// ---------------------------------------------------------------------------
__global__ __launch_bounds__(256, 2) void flash8(const u16* __restrict__ q_t,
                                                 const u16* __restrict__ k_t,
                                                 const u16* __restrict__ v_,
                                                 u16* __restrict__ opart,
                                                 float2* __restrict__ ml) {
  __shared__ u16 __align__(16) Kls[2][32 * 256];  // [buf][n][c] swizzled
  __shared__ u16 __align__(16) Vls[2][128 * 64];  // [buf][c-pair rows]

  const int t = threadIdx.x, w = t >> 6, lane = t & 63;
  const int l31 = lane & 31, l5 = lane >> 5;

  // XCD swizzle: xcd owns (b, quarter-pair) -> K/V/Q working set ~4MB in L2.
  const int linear = blockIdx.x;
  const int xcd = linear & 7, slot = linear >> 3;  // slot in [0,64)
  const int b = xcd >> 1;
  const int q = (xcd & 1) * 2 + (slot >> 5);  // key-quarter 0..3
  const int mblk = slot & 31;
  const int m0 = mblk * 128;
  const int nbase = q * 1024;

  const u16* Qb = q_t + (size_t)b * NSEQ * CD;
  const u16* Kb = k_t + (size_t)b * NSEQ * CD;
  const u16* Vb = v_ + (size_t)b * CD * NSEQ;

  const int mrow = m0 + w * 32 + l31;  // global query index

  // Q fragments in registers (B-operand for S), K=256
  short8 qf[16];
#pragma unroll
  for (int kc = 0; kc < 16; ++kc)
    qf[kc] = *(const short8*)(Qb + (size_t)mrow * CD + kc * 16 + l5 * 8);

  // --- per-lane staging address constants ---
  // K: wave w stages rows w*8 + j*2 + l5 (2 rows per 1KB DMA, 4 DMAs)
  // V: paired-row layout: LDS row c2 (128 B) holds c = 2*c2 + (ch>>2),
  //    n-span (ch&3)*8..+8, phys chunk = ch ^ (c2&7). DMA lane covers
  //    row c2 = w*32 + j*8 + (lane>>3), phys chunk lane&7.
  int krow[4];
  const u16* ksrc[4];
#pragma unroll
  for (int j = 0; j < 4; ++j) {
    krow[j] = w * 8 + j * 2 + l5;
    ksrc[j] = Kb + (size_t)krow[j] * CD + ((l31 ^ (krow[j] & 7)) * 8);
  }
  const u16* vsrc[4];
#pragma unroll
  for (int j = 0; j < 4; ++j) {
    int c2 = w * 32 + j * 8 + (lane >> 3);
    int chl = (lane & 7) ^ (c2 & 7);
    int c = (c2 << 1) | (chl >> 2);
    vsrc[j] = Vb + (size_t)c * NSEQ + (chl & 3) * 8;
  }

  // stage tile 0 into buf 0
#pragma unroll
  for (int j = 0; j < 4; ++j) {
    async16(ksrc[j] + (size_t)nbase * CD, &Kls[0][(w * 8 + j * 2) * 256]);
    async16(vsrc[j] + nbase, &Vls[0][(w * 32 + j * 8) * 64]);
  }

  float mst = -3.0e38f, lst = 0.f;  // lst = per-lane partial (own half)
  f32x16 oa[8];  // O[c = ct*32 + rowmap][m = mrow]
#pragma unroll
  for (int i = 0; i < 8; ++i)
#pragma unroll
    for (int r = 0; r < 16; ++r) oa[i][r] = 0.f;

  for (int tt = 0; tt < 32; ++tt) {
    const int cur = tt & 1;
    // drain: tile tt's DMA complete; prior reads of buf[cur] done
    __builtin_amdgcn_s_waitcnt(0);
    __syncthreads();
    if (tt + 1 < 32) {
      const int n0 = nbase + (tt + 1) * 32;
      const int nxt = cur ^ 1;
#pragma unroll
      for (int j = 0; j < 4; ++j) {
        async16(ksrc[j] + (size_t)n0 * CD, &Kls[nxt][(w * 8 + j * 2) * 256]);
        async16(vsrc[j] + n0, &Vls[nxt][(w * 32 + j * 8) * 64]);
      }
    }
    // ---- S = K . Q^T : 32n x own 32m, K=256 ----
    f32x16 sa;
#pragma unroll
    for (int i = 0; i < 16; ++i) sa[i] = 0.f;
#pragma unroll
    for (int kc = 0; kc < 16; ++kc) {
      short8 a =
          *(const short8*)(&Kls[cur][l31 * 256 + (((kc * 2 + l5) ^ (l31 & 7)) * 8)]);
      sa = MFMA32(a, qf[kc], sa, 0, 0, 0);
    }
    // ---- softmax, fully in-wave (m = l31; l5 halves merge via xor32) ----
    float rm = sa[0];
#pragma unroll
    for (int i = 1; i < 16; ++i) rm = fmaxf(rm, sa[i]);
    rm = fmaxf(rm, __shfl_xor(rm, 32));
    float mnew = fmaxf(mst, rm * CF);
    float al = exp2f(mst - mnew);
    mst = mnew;
    // p -> packed bf16 dwords; lane holds n = 8*gg + 4*l5 + 2x + {0,1}
    u32 d[4][2];
    float ls = 0.f;
#pragma unroll
    for (int gg = 0; gg < 4; ++gg) {
      float p0 = exp2f(sa[gg * 4 + 0] * CF - mnew);
      float p1 = exp2f(sa[gg * 4 + 1] * CF - mnew);
      float p2 = exp2f(sa[gg * 4 + 2] * CF - mnew);
      float p3 = exp2f(sa[gg * 4 + 3] * CF - mnew);
      ls += (p0 + p1) + (p2 + p3);
      d[gg][0] = pk2bf(p0, p1);
      d[gg][1] = pk2bf(p2, p3);
    }
    // per-lane partial: al/mnew uniform across l5 pair -> merge once at end
    lst = lst * al + ls;
    // ---- rescale O only when the running max moved (rare) ----
    if (__ballot(al != 1.0f)) {
#pragma unroll
      for (int i = 0; i < 8; ++i)
#pragma unroll
        for (int r = 0; r < 16; ++r) oa[i][r] *= al;
    }
    // ---- build P B-frags via l5-partner exchange (4 shfl_xor) ----
    short8 pf[2];
#pragma unroll
    for (int f = 0; f < 2; ++f) {
      const int g0 = f * 2;
      u32 sx0 = l5 ? d[g0][0] : d[g0 + 1][0];
      u32 sx1 = l5 ? d[g0][1] : d[g0 + 1][1];
      u32 e0 = (u32)__shfl_xor((int)sx0, 32);
      u32 e1 = (u32)__shfl_xor((int)sx1, 32);
      union {
        u32 u[4];
        short8 s8;
      } cv;
      cv.u[0] = l5 ? e0 : d[g0][0];
      cv.u[1] = l5 ? e1 : d[g0][1];
      cv.u[2] = l5 ? d[g0 + 1][0] : e0;
      cv.u[3] = l5 ? d[g0 + 1][1] : e1;
      pf[f] = cv.s8;
    }
    // ---- O += V . P : full 256 c (8 subtiles) x 32 keys ----
#pragma unroll
    for (int f = 0; f < 2; ++f) {
#pragma unroll
      for (int ct = 0; ct < 8; ++ct) {
        // paired-row V read: c = ct*32+l31 -> row c2 = ct*16+(l31>>1),
        // logical chunk = (c&1)*4 + f*2 + l5, phys = chunk ^ (c2&7)
        int c2r = ct * 16 + (l31 >> 1);
        int chl = ((l31 & 1) << 2) | (f * 2 + l5);
        short8 vf =
            *(const short8*)(&Vls[cur][c2r * 64 + ((chl ^ (c2r & 7)) * 8)]);
        oa[ct] = MFMA32(vf, pf[f], oa[ct], 0, 0, 0);
      }
    }
  }

  // ---- merge per-lane l partials across the l5 pair (deferred from loop) ----
  lst += __shfl_xor(lst, 32);

  // ---- finalize: per-stream normalized O -> bf16; (m,l) for merge ----
  float inv = 1.0f / lst;
  u16* dst = opart + ((size_t)(q * 4 + b) * NSEQ + mrow) * CD;
#pragma unroll
  for (int ct = 0; ct < 8; ++ct)
#pragma unroll
    for (int gg = 0; gg < 4; ++gg) {
      short4v pk;
#pragma unroll
      for (int r = 0; r < 4; ++r) pk[r] = (short)f2bf(oa[ct][gg * 4 + r] * inv);
      *(short4v*)(dst + ct * 32 + gg * 8 + l5 * 4) = pk;
    }
  if (lane < 32)
    ml[(size_t)(q * 4 + b) * NSEQ + mrow] = make_float2(mst, lst);
}

// ---------------------------------------------------------------------------
// out projection + 4-stream split-key merge folded into B-tile staging.
// ---------------------------------------------------------------------------
__global__ __launch_bounds__(512, 1) void out_gemm6(
    const u16* __restrict__ wo, const float* __restrict__ out_b,
    const u16* __restrict__ opart, const float2* __restrict__ ml,
    float* __restrict__ out) {
  __shared__ u16 __align__(16) Wls[128 * 256];
  __shared__ u16 __align__(16) Bls[128 * 256];
  const int t = threadIdx.x, w = t >> 6, lane = t & 63;
  const int l31 = lane & 31, l5 = lane >> 5;
  const int os = w & 3, nh = w >> 2;
  const int n0 = blockIdx.x * 128, o0 = blockIdx.y * 128, b = blockIdx.z;
#pragma unroll
  for (int j = 0; j < 8; ++j) {
    int r = w * 16 + j * 2 + l5;
    async16(wo + (size_t)(o0 + r) * CD + ((l31 ^ (r & 7)) * 8),
            Wls + (w * 16 + j * 2) * 256);
  }
#pragma unroll
  for (int i = 0; i < 8; ++i) {
    int idx = i * 512 + t;
    int r = idx >> 5, p = idx & 31;
    int n = n0 + r;
    float2 st[4];
#pragma unroll
    for (int qq = 0; qq < 4; ++qq) st[qq] = ml[(size_t)(qq * 4 + b) * NSEQ + n];
    float M = fmaxf(fmaxf(st[0].x, st[1].x), fmaxf(st[2].x, st[3].x));
    float wt[4], tot = 0.f;
#pragma unroll
    for (int qq = 0; qq < 4; ++qq) {
      wt[qq] = st[qq].y * exp2f(st[qq].x - M);
      tot += wt[qq];
    }
    float inv = 1.0f / tot;
    float acc[8] = {};
#pragma unroll
    for (int qq = 0; qq < 4; ++qq) {
      float wq_ = wt[qq] * inv;
      short8 xq =
          *(const short8*)(opart + ((size_t)(qq * 4 + b) * NSEQ + n) * CD + p * 8);
#pragma unroll
      for (int e = 0; e < 8; ++e) acc[e] += wq_ * bf2f(xq[e]);
    }
    short8 om;
#pragma unroll
    for (int e = 0; e < 8; ++e) om[e] = (short)f2bf(acc[e]);
    *(short8*)(Bls + r * 256 + ((p ^ (r & 7)) * 8)) = om;
  }
  __builtin_amdgcn_s_waitcnt(0);
  __syncthreads();
  f32x16 acc0, acc1;
#pragma unroll
  for (int i = 0; i < 16; ++i) {
    acc0[i] = 0.f;
    acc1[i] = 0.f;
  }
  const int ra = os * 32 + l31;
  const int rb0 = nh * 64 + l31, rb1 = rb0 + 32;
#pragma unroll
  for (int kc = 0; kc < 16; ++kc) {
    short8 a = *(const short8*)(Wls + ra * 256 + (((kc * 2 + l5) ^ (ra & 7)) * 8));
    short8 b0 = *(const short8*)(Bls + rb0 * 256 + (((kc * 2 + l5) ^ (rb0 & 7)) * 8));
    short8 b1 = *(const short8*)(Bls + rb1 * 256 + (((kc * 2 + l5) ^ (rb1 & 7)) * 8));
    acc0 = MFMA32(a, b0, acc0, 0, 0, 0);
    acc1 = MFMA32(a, b1, acc1, 0, 0, 0);
  }
  const int obase = o0 + os * 32;
#pragma unroll
  for (int na = 0; na < 2; ++na) {
    f32x16& acc = na ? acc1 : acc0;
    const int n_g = n0 + nh * 64 + na * 32 + l31;
#pragma unroll
    for (int g = 0; g < 4; ++g) {
      float4 bv = *(const float4*)(out_b + obase + g * 8 + l5 * 4);
      const float* bp = (const float*)&bv;
#pragma unroll
      for (int r = 0; r < 4; ++r) {
        int o = obase + g * 8 + l5 * 4 + r;
        out[((size_t)b * CD + o) * NSEQ + n_g] = acc[g * 4 + r] + bp[r];
      }
    }
  }
}

// ---------------------------------------------------------------------------
extern "C" void kernel_launch(void* const* d_in, const int* in_sizes, int n_in,
                              void* d_out, int out_size, void* d_ws,
                              size_t ws_size, hipStream_t stream) {
  const float* x = (const float*)d_in[0];
  const float* qkv_w = (const float*)d_in[1];
  const float* qkv_b = (const float*)d_in[2];
  const float* out_w = (const float*)d_in[3];
  const float* out_b = (const float*)d_in[4];
  float* out = (float*)d_out;

  const size_t SZ = (size_t)4 * NSEQ * CD;  // elems per (b,4096,256) bf16
  u16* x_t = (u16*)d_ws;
  u16* q_t = x_t + SZ;
  u16* k_t = q_t + SZ;
  u16* v_ = k_t + SZ;
  u16* opart = v_ + SZ;              // 4 key-stream quarters, 4*SZ
  u16* wq = opart + 4 * SZ;          // 768*256
  u16* wo = wq + 768 * CD;           // 256*256
  float2* ml = (float2*)(wo + CD * CD);  // 4*4*4096 float2

  xpose_cast<<<dim3(64, 4, 4), dim3(256), 0, stream>>>(x, x_t, qkv_w, out_w,
                                                       wq, wo);
  qkv_gemm3<<<dim3(32, 6, 4), dim3(512), 0, stream>>>(wq, qkv_b, x_t, q_t, k_t,
                                                      v_);
  flash8<<<dim3(512), dim3(256), 0, stream>>>(q_t, k_t, v_, opart, ml);
  out_gemm6<<<dim3(32, 2, 4), dim3(512), 0, stream>>>(wo, out_b, opart, ml,
                                                      out);
}

// Round 8
// 201.228 us; speedup vs baseline: 2.1563x; 1.0484x over previous
//
#include <hip/hip_runtime.h>
#include <hip/hip_bf16.h>

typedef unsigned short u16;
typedef unsigned int u32;
typedef __attribute__((ext_vector_type(8))) short short8;   // 8 x bf16 frag
typedef __attribute__((ext_vector_type(4))) short short4v;  // 4 x bf16 pack
typedef __attribute__((ext_vector_type(16))) float f32x16;  // 32x32 acc

#define MFMA32 __builtin_amdgcn_mfma_f32_32x32x16_bf16

#define NSEQ 4096
#define CD 256
// (1/sqrt(256)) * log2(e) = 0.0625 * 1.4426950408889634  -- EXACT.
#define CF 0.09016844005556021f

__device__ __forceinline__ u16 f2bf(float f) {
  u32 u = __float_as_uint(f);
  u += 0x7fffu + ((u >> 16) & 1u);  // RNE
  return (u16)(u >> 16);
}
__device__ __forceinline__ float bf2f(short s) {
  return __uint_as_float(((u32)(u16)s) << 16);
}
// HW packed f32x2 -> bf16x2 (gfx950 v_cvt_pk_bf16_f32), RNE
__device__ __forceinline__ u32 pk2bf(float a, float b) {
  union {
    __hip_bfloat162 h;
    u32 u;
  } cv;
  cv.h = __float22bfloat162_rn(make_float2(a, b));
  return cv.u;
}
// async global -> LDS DMA, 16B per lane; LDS dest = wave-uniform base + lane*16
__device__ __forceinline__ void async16(const void* g, void* l) {
  __builtin_amdgcn_global_load_lds(
      (const __attribute__((address_space(1))) u32*)g,
      (__attribute__((address_space(3))) u32*)l, 16, 0, 0);
}

// ---------------------------------------------------------------------------
// transpose-cast x: (b, 256, 4096) f32 -> x_t (b, 4096, 256) bf16
// + folded weight cast (1024 blocks x 256 weight elems = exactly 768*256+256*256)
// (unchanged)
// ---------------------------------------------------------------------------
__global__ __launch_bounds__(256) void xpose_cast(const float* __restrict__ x,
                                                  u16* __restrict__ x_t,
                                                  const float* __restrict__ qkv_w,
                                                  const float* __restrict__ out_w,
                                                  u16* __restrict__ wq,
                                                  u16* __restrict__ wo) {
  __shared__ float tile[64][65];
  const int t = threadIdx.x;
  // ---- weight cast slice ----
  {
    int lin = blockIdx.x + 64 * (blockIdx.y + 4 * blockIdx.z);
    int widx = lin * 256 + t;
    if (widx < 768 * CD)
      wq[widx] = f2bf(qkv_w[widx]);
    else
      wo[widx - 768 * CD] = f2bf(out_w[widx - 768 * CD]);
  }
  // ---- transpose-cast ----
  const int b = blockIdx.z;
  const int n0 = blockIdx.x * 64, c0 = blockIdx.y * 64;
  const float* xb = x + (size_t)b * CD * NSEQ;
  const int cr = t >> 4, nc4 = (t & 15) * 4;
#pragma unroll
  for (int i = 0; i < 4; ++i) {
    int c = cr + 16 * i;
    float4 v = *(const float4*)(xb + (size_t)(c0 + c) * NSEQ + n0 + nc4);
    tile[c][nc4 + 0] = v.x;
    tile[c][nc4 + 1] = v.y;
    tile[c][nc4 + 2] = v.z;
    tile[c][nc4 + 3] = v.w;
  }
  __syncthreads();
  const int n = t & 63, cc = (t >> 6) * 16;
  u16* dst = x_t + (size_t)b * NSEQ * CD + (size_t)(n0 + n) * CD + c0 + cc;
#pragma unroll
  for (int j = 0; j < 4; ++j) {
    short4v pv;
#pragma unroll
    for (int r = 0; r < 4; ++r) pv[r] = (short)f2bf(tile[cc + 4 * j + r][n]);
    *(short4v*)(dst + 4 * j) = pv;
  }
}

// ---------------------------------------------------------------------------
// QKV projection v4: K-SPLIT. The v3 structure used 128 KB LDS (full K=256
// tiles) -> 1 block/CU -> the vmcnt(0) stage drain was fully exposed, 3 grid
// rounds deep. Split K into two 128-halves: Wls/Bls are 128x128 (32 KB each,
// 64 KB total) -> __launch_bounds__(512,2) -> 2 blocks/CU; one block's MFMA
// phase covers the other's staging. Same DMA bytes, same acc math (K-order
// split), same epilogue.
// Staging: rows are 256 B; one 1-KB DMA = 4 rows; lane l covers row
// base+(l>>4), phys chunk l&15, source chunk (l&15)^(row&7) (xor involution
// matches the frag-read swizzle chunk^(row&7), chunks now 0..15).
// ---------------------------------------------------------------------------
__global__ __launch_bounds__(512, 2) void qkv_gemm4(
    const u16* __restrict__ wq, const float* __restrict__ qkv_b,
    const u16* __restrict__ x_t, u16* __restrict__ q_t, u16* __restrict__ k_t,
    u16* __restrict__ v_) {
  __shared__ u16 __align__(16) Wls[128 * 128];
  __shared__ u16 __align__(16) Bls[128 * 128];
  const int t = threadIdx.x, w = t >> 6, lane = t & 63;
  const int l31 = lane & 31, l5 = lane >> 5;
  const int os = w & 3, nh = w >> 2;
  const int n0 = blockIdx.x * 128, o0 = blockIdx.y * 128, b = blockIdx.z;
  const u16* Xb = x_t + (size_t)b * NSEQ * CD;

  // per-lane staging constants: row r = w*16 + j*4 + (lane>>4), chunk l&15
  const int srow = w * 16 + (lane >> 4);        // + j*4
  const int schk = lane & 15;
  f32x16 acc0, acc1;
#pragma unroll
  for (int i = 0; i < 16; ++i) {
    acc0[i] = 0.f;
    acc1[i] = 0.f;
  }
  const int ra = os * 32 + l31;
  const int rb0 = nh * 64 + l31, rb1 = rb0 + 32;

#pragma unroll
  for (int kh = 0; kh < 2; ++kh) {
    if (kh) __syncthreads();  // all reads of buffers done before restage
#pragma unroll
    for (int j = 0; j < 4; ++j) {
      int r = srow + j * 4;
      async16(wq + (size_t)(o0 + r) * CD + kh * 128 + ((schk ^ (r & 7)) * 8),
              Wls + (w * 16 + j * 4) * 128);
      async16(Xb + (size_t)(n0 + r) * CD + kh * 128 + ((schk ^ (r & 7)) * 8),
              Bls + (w * 16 + j * 4) * 128);
    }
    __builtin_amdgcn_s_waitcnt(0);
    __syncthreads();
#pragma unroll
    for (int kc = 0; kc < 8; ++kc) {
      short8 a =
          *(const short8*)(Wls + ra * 128 + (((kc * 2 + l5) ^ (ra & 7)) * 8));
      short8 b0 =
          *(const short8*)(Bls + rb0 * 128 + (((kc * 2 + l5) ^ (rb0 & 7)) * 8));
      short8 b1 =
          *(const short8*)(Bls + rb1 * 128 + (((kc * 2 + l5) ^ (rb1 & 7)) * 8));
      acc0 = MFMA32(a, b0, acc0, 0, 0, 0);
      acc1 = MFMA32(a, b1, acc1, 0, 0, 0);
    }
  }

  const int otype = blockIdx.y >> 1;  // 0=Q 1=K 2=V
  const int obase = o0 + os * 32;
#pragma unroll
  for (int na = 0; na < 2; ++na) {
    f32x16& acc = na ? acc1 : acc0;
    const int n_g = n0 + nh * 64 + na * 32 + l31;
    if (otype < 2) {
      u16* dst = (otype == 0 ? q_t : k_t) + (size_t)b * NSEQ * CD +
                 (size_t)n_g * CD + (obase - otype * 256);
#pragma unroll
      for (int g = 0; g < 4; ++g) {
        float4 bv = *(const float4*)(qkv_b + obase + g * 8 + l5 * 4);
        const float* bp = (const float*)&bv;
        short4v pk;
#pragma unroll
        for (int r = 0; r < 4; ++r) pk[r] = (short)f2bf(acc[g * 4 + r] + bp[r]);
        *(short4v*)(dst + g * 8 + l5 * 4) = pk;
      }
    } else {
      u16* dst = v_ + (size_t)b * CD * NSEQ;
#pragma unroll
      for (int g = 0; g < 4; ++g) {
        float4 bv = *(const float4*)(qkv_b + obase + g * 8 + l5 * 4);
        const float* bp = (const float*)&bv;
#pragma unroll
        for (int r = 0; r < 4; ++r) {
          int c = obase - 512 + g * 8 + l5 * 4 + r;
          dst[(size_t)c * NSEQ + n_g] = f2bf(acc[g * 4 + r] + bp[r]);
        }
      }
    }
  }
}

// ---------------------------------------------------------------------------
// Flash attention v8b (unchanged champion, 113 us): 32m/wave 32x32 MFMA,
// K+V double-buffered LDS, per-lane lst partials merged once at finalize.
// ---------------------------------------------------------------------------
__global__ __launch_bounds__(256, 2) void flash8(const u16* __restrict__ q_t,
                                                 const u16* __restrict__ k_t,
                                                 const u16* __restrict__ v_,
                                                 u16* __restrict__ opart,
                                                 float2* __restrict__ ml) {
  __shared__ u16 __align__(16) Kls[2][32 * 256];  // [buf][n][c] swizzled
  __shared__ u16 __align__(16) Vls[2][128 * 64];  // [buf][c-pair rows]

  const int t = threadIdx.x, w = t >> 6, lane = t & 63;
  const int l31 = lane & 31, l5 = lane >> 5;

  const int linear = blockIdx.x;
  const int xcd = linear & 7, slot = linear >> 3;  // slot in [0,64)
  const int b = xcd >> 1;
  const int q = (xcd & 1) * 2 + (slot >> 5);  // key-quarter 0..3
  const int mblk = slot & 31;
  const int m0 = mblk * 128;
  const int nbase = q * 1024;

  const u16* Qb = q_t + (size_t)b * NSEQ * CD;
  const u16* Kb = k_t + (size_t)b * NSEQ * CD;
  const u16* Vb = v_ + (size_t)b * CD * NSEQ;

  const int mrow = m0 + w * 32 + l31;  // global query index

  short8 qf[16];
#pragma unroll
  for (int kc = 0; kc < 16; ++kc)
    qf[kc] = *(const short8*)(Qb + (size_t)mrow * CD + kc * 16 + l5 * 8);

  int krow[4];
  const u16* ksrc[4];
#pragma unroll
  for (int j = 0; j < 4; ++j) {
    krow[j] = w * 8 + j * 2 + l5;
    ksrc[j] = Kb + (size_t)krow[j] * CD + ((l31 ^ (krow[j] & 7)) * 8);
  }
  const u16* vsrc[4];
#pragma unroll
  for (int j = 0; j < 4; ++j) {
    int c2 = w * 32 + j * 8 + (lane >> 3);
    int chl = (lane & 7) ^ (c2 & 7);
    int c = (c2 << 1) | (chl >> 2);
    vsrc[j] = Vb + (size_t)c * NSEQ + (chl & 3) * 8;
  }

#pragma unroll
  for (int j = 0; j < 4; ++j) {
    async16(ksrc[j] + (size_t)nbase * CD, &Kls[0][(w * 8 + j * 2) * 256]);
    async16(vsrc[j] + nbase, &Vls[0][(w * 32 + j * 8) * 64]);
  }

  float mst = -3.0e38f, lst = 0.f;  // lst = per-lane partial (own half)
  f32x16 oa[8];
#pragma unroll
  for (int i = 0; i < 8; ++i)
#pragma unroll
    for (int r = 0; r < 16; ++r) oa[i][r] = 0.f;

  for (int tt = 0; tt < 32; ++tt) {
    const int cur = tt & 1;
    __builtin_amdgcn_s_waitcnt(0);
    __syncthreads();
    if (tt + 1 < 32) {
      const int n0 = nbase + (tt + 1) * 32;
      const int nxt = cur ^ 1;
#pragma unroll
      for (int j = 0; j < 4; ++j) {
        async16(ksrc[j] + (size_t)n0 * CD, &Kls[nxt][(w * 8 + j * 2) * 256]);
        async16(vsrc[j] + n0, &Vls[nxt][(w * 32 + j * 8) * 64]);
      }
    }
    f32x16 sa;
#pragma unroll
    for (int i = 0; i < 16; ++i) sa[i] = 0.f;
#pragma unroll
    for (int kc = 0; kc < 16; ++kc) {
      short8 a =
          *(const short8*)(&Kls[cur][l31 * 256 + (((kc * 2 + l5) ^ (l31 & 7)) * 8)]);
      sa = MFMA32(a, qf[kc], sa, 0, 0, 0);
    }
    float rm = sa[0];
#pragma unroll
    for (int i = 1; i < 16; ++i) rm = fmaxf(rm, sa[i]);
    rm = fmaxf(rm, __shfl_xor(rm, 32));
    float mnew = fmaxf(mst, rm * CF);
    float al = exp2f(mst - mnew);
    mst = mnew;
    u32 d[4][2];
    float ls = 0.f;
#pragma unroll
    for (int gg = 0; gg < 4; ++gg) {
      float p0 = exp2f(sa[gg * 4 + 0] * CF - mnew);
      float p1 = exp2f(sa[gg * 4 + 1] * CF - mnew);
      float p2 = exp2f(sa[gg * 4 + 2] * CF - mnew);
      float p3 = exp2f(sa[gg * 4 + 3] * CF - mnew);
      ls += (p0 + p1) + (p2 + p3);
      d[gg][0] = pk2bf(p0, p1);
      d[gg][1] = pk2bf(p2, p3);
    }
    lst = lst * al + ls;
    if (__ballot(al != 1.0f)) {
#pragma unroll
      for (int i = 0; i < 8; ++i)
#pragma unroll
        for (int r = 0; r < 16; ++r) oa[i][r] *= al;
    }
    short8 pf[2];
#pragma unroll
    for (int f = 0; f < 2; ++f) {
      const int g0 = f * 2;
      u32 sx0 = l5 ? d[g0][0] : d[g0 + 1][0];
      u32 sx1 = l5 ? d[g0][1] : d[g0 + 1][1];
      u32 e0 = (u32)__shfl_xor((int)sx0, 32);
      u32 e1 = (u32)__shfl_xor((int)sx1, 32);
      union {
        u32 u[4];
        short8 s8;
      } cv;
      cv.u[0] = l5 ? e0 : d[g0][0];
      cv.u[1] = l5 ? e1 : d[g0][1];
      cv.u[2] = l5 ? d[g0 + 1][0] : e0;
      cv.u[3] = l5 ? d[g0 + 1][1] : e1;
      pf[f] = cv.s8;
    }
#pragma unroll
    for (int f = 0; f < 2; ++f) {
#pragma unroll
      for (int ct = 0; ct < 8; ++ct) {
        int c2r = ct * 16 + (l31 >> 1);
        int chl = ((l31 & 1) << 2) | (f * 2 + l5);
        short8 vf =
            *(const short8*)(&Vls[cur][c2r * 64 + ((chl ^ (c2r & 7)) * 8)]);
        oa[ct] = MFMA32(vf, pf[f], oa[ct], 0, 0, 0);
      }
    }
  }

  lst += __shfl_xor(lst, 32);

  float inv = 1.0f / lst;
  u16* dst = opart + ((size_t)(q * 4 + b) * NSEQ + mrow) * CD;
#pragma unroll
  for (int ct = 0; ct < 8; ++ct)
#pragma unroll
    for (int gg = 0; gg < 4; ++gg) {
      short4v pk;
#pragma unroll
      for (int r = 0; r < 4; ++r) pk[r] = (short)f2bf(oa[ct][gg * 4 + r] * inv);
      *(short4v*)(dst + ct * 32 + gg * 8 + l5 * 4) = pk;
    }
  if (lane < 32)
    ml[(size_t)(q * 4 + b) * NSEQ + mrow] = make_float2(mst, lst);
}

// ---------------------------------------------------------------------------
// out projection v7: K-SPLIT (same transform as qkv_gemm4). Wls/Bls 128x128
// (64 KB total) -> 2 blocks/CU. The merge (split-key combine) computes each
// 128-col half of Bls just before that half's MFMA pass; ml weights are
// recomputed per half (cheap, broadcast loads).
// ---------------------------------------------------------------------------
__global__ __launch_bounds__(512, 2) void out_gemm7(
    const u16* __restrict__ wo, const float* __restrict__ out_b,
    const u16* __restrict__ opart, const float2* __restrict__ ml,
    float* __restrict__ out) {
  __shared__ u16 __align__(16) Wls[128 * 128];
  __shared__ u16 __align__(16) Bls[128 * 128];
  const int t = threadIdx.x, w = t >> 6, lane = t & 63;
  const int l31 = lane & 31, l5 = lane >> 5;
  const int os = w & 3, nh = w >> 2;
  const int n0 = blockIdx.x * 128, o0 = blockIdx.y * 128, b = blockIdx.z;

  const int srow = w * 16 + (lane >> 4);  // + j*4 (staging row)
  const int schk = lane & 15;
  f32x16 acc0, acc1;
#pragma unroll
  for (int i = 0; i < 16; ++i) {
    acc0[i] = 0.f;
    acc1[i] = 0.f;
  }
  const int ra = os * 32 + l31;
  const int rb0 = nh * 64 + l31, rb1 = rb0 + 32;

#pragma unroll
  for (int kh = 0; kh < 2; ++kh) {
    if (kh) __syncthreads();  // all reads of buffers done before restage
    // ---- W half stage (DMA) ----
#pragma unroll
    for (int j = 0; j < 4; ++j) {
      int r = srow + j * 4;
      async16(wo + (size_t)(o0 + r) * CD + kh * 128 + ((schk ^ (r & 7)) * 8),
              Wls + (w * 16 + j * 4) * 128);
    }
    // ---- B half: 4-stream split-key merge -> Bls[r][p' chunks] ----
#pragma unroll
    for (int i = 0; i < 4; ++i) {
      int idx = i * 512 + t;
      int r = idx >> 4, pp = idx & 15;  // r in [0,128), pp in [0,16)
      int n = n0 + r;
      float2 st[4];
#pragma unroll
      for (int qq = 0; qq < 4; ++qq)
        st[qq] = ml[(size_t)(qq * 4 + b) * NSEQ + n];
      float M = fmaxf(fmaxf(st[0].x, st[1].x), fmaxf(st[2].x, st[3].x));
      float wt[4], tot = 0.f;
#pragma unroll
      for (int qq = 0; qq < 4; ++qq) {
        wt[qq] = st[qq].y * exp2f(st[qq].x - M);
        tot += wt[qq];
      }
      float inv = 1.0f / tot;
      float acc[8] = {};
#pragma unroll
      for (int qq = 0; qq < 4; ++qq) {
        float wq_ = wt[qq] * inv;
        short8 xq = *(const short8*)(opart +
                                     ((size_t)(qq * 4 + b) * NSEQ + n) * CD +
                                     kh * 128 + pp * 8);
#pragma unroll
        for (int e = 0; e < 8; ++e) acc[e] += wq_ * bf2f(xq[e]);
      }
      short8 om;
#pragma unroll
      for (int e = 0; e < 8; ++e) om[e] = (short)f2bf(acc[e]);
      *(short8*)(Bls + r * 128 + ((pp ^ (r & 7)) * 8)) = om;
    }
    __builtin_amdgcn_s_waitcnt(0);
    __syncthreads();
#pragma unroll
    for (int kc = 0; kc < 8; ++kc) {
      short8 a =
          *(const short8*)(Wls + ra * 128 + (((kc * 2 + l5) ^ (ra & 7)) * 8));
      short8 b0 =
          *(const short8*)(Bls + rb0 * 128 + (((kc * 2 + l5) ^ (rb0 & 7)) * 8));
      short8 b1 =
          *(const short8*)(Bls + rb1 * 128 + (((kc * 2 + l5) ^ (rb1 & 7)) * 8));
      acc0 = MFMA32(a, b0, acc0, 0, 0, 0);
      acc1 = MFMA32(a, b1, acc1, 0, 0, 0);
    }
  }

  const int obase = o0 + os * 32;
#pragma unroll
  for (int na = 0; na < 2; ++na) {
    f32x16& acc = na ? acc1 : acc0;
    const int n_g = n0 + nh * 64 + na * 32 + l31;
#pragma unroll
    for (int g = 0; g < 4; ++g) {
      float4 bv = *(const float4*)(out_b + obase + g * 8 + l5 * 4);
      const float* bp = (const float*)&bv;
#pragma unroll
      for (int r = 0; r < 4; ++r) {
        int o = obase + g * 8 + l5 * 4 + r;
        out[((size_t)b * CD + o) * NSEQ + n_g] = acc[g * 4 + r] + bp[r];
      }
    }
  }
}

// ---------------------------------------------------------------------------
extern "C" void kernel_launch(void* const* d_in, const int* in_sizes, int n_in,
                              void* d_out, int out_size, void* d_ws,
                              size_t ws_size, hipStream_t stream) {
  const float* x = (const float*)d_in[0];
  const float* qkv_w = (const float*)d_in[1];
  const float* qkv_b = (const float*)d_in[2];
  const float* out_w = (const float*)d_in[3];
  const float* out_b = (const float*)d_in[4];
  float* out = (float*)d_out;

  const size_t SZ = (size_t)4 * NSEQ * CD;  // elems per (b,4096,256) bf16
  u16* x_t = (u16*)d_ws;
  u16* q_t = x_t + SZ;
  u16* k_t = q_t + SZ;
  u16* v_ = k_t + SZ;
  u16* opart = v_ + SZ;              // 4 key-stream quarters, 4*SZ
  u16* wq = opart + 4 * SZ;          // 768*256
  u16* wo = wq + 768 * CD;           // 256*256
  float2* ml = (float2*)(wo + CD * CD);  // 4*4*4096 float2

  xpose_cast<<<dim3(64, 4, 4), dim3(256), 0, stream>>>(x, x_t, qkv_w, out_w,
                                                       wq, wo);
  qkv_gemm4<<<dim3(32, 6, 4), dim3(512), 0, stream>>>(wq, qkv_b, x_t, q_t, k_t,
                                                      v_);
  flash8<<<dim3(512), dim3(256), 0, stream>>>(q_t, k_t, v_, opart, ml);
  out_gemm7<<<dim3(32, 2, 4), dim3(512), 0, stream>>>(wo, out_b, opart, ml,
                                                      out);
}